// Round 8
// baseline (200.802 us; speedup 1.0000x reference)
//
#include <hip/hip_runtime.h>
#include <stdint.h>

// ---------------------------------------------------------------------------
// d128snn_delays, round 18 = R17 (184.3us best) + fir1/fir2 reworked to
// 32-col blocks (grid 1024, LDS 36.8KB, lb(256,4) -> 16 waves/CU, 2x TLP).
// Theory: R17's band-skip (-46% MFMA, only -2us) proved fir is latency/
// barrier-bound, not MFMA-bound -> raise wave-level parallelism.
// Measured-dead-end ledger:
//   - inline BN in GEMM staging (R6): +VALU in K-loop critical path, net -.
//   - cooperative mega-kernel (R9): grid.sync() ~110us each on gfx950 -> 5x.
//   - XCD-aware swizzle (R10): serializes A-fill through one XCD's L2. -10us.
//   - R12 device-scope semaphore BN fusion: +55us PER SYNC. Never again.
//   - R14 gemm dbuf-B: half-pipeline, no latency hidden, LDS 2x. Negative.
//   - R14/R15 fir poison-mask in prefetch path: ~+5us. MFMA-skip != load-skip.
// R17 fir MFMA band-skip: kept (53/98 MFMAs, constant-folded guards).
// Same-code noise band: +-2.5us. Accept threshold: >3us.
// Budget: ~42us harness fill + ~73us kernels + ~45us dispatch gaps.
// ---------------------------------------------------------------------------

#define T_LEN 100
#define B_SZ  128
#define M_ROWS 12800
#define R_RANK 4
#define K_FIR 448

typedef __bf16 v8bf __attribute__((ext_vector_type(8)));
typedef float  v4f  __attribute__((ext_vector_type(4)));
typedef unsigned int uint32;
typedef unsigned short ushort_t;

// PHI[tau][r] = exp(-u^2/2) * T_r(u), u = (tau-12)/12  (Chebyshev basis)
struct PhiT { float v[25][R_RANK]; };
constexpr double cexp_(double x) {
  double s = 1.0, t = 1.0;
  for (int n = 1; n < 30; ++n) { t = t * x / n; s += t; }
  return s;
}
constexpr PhiT make_phi() {
  PhiT P{};
  for (int tau = 0; tau < 25; ++tau) {
    double u = (tau - 12) / 12.0;
    double g = cexp_(-0.5 * u * u);
    double T0 = 1.0, T1 = u;
    P.v[tau][0] = (float)(g * T0);
    P.v[tau][1] = (float)(g * T1);
    for (int r = 2; r < R_RANK; ++r) {
      double T2 = 2.0 * u * T1 - T0;
      P.v[tau][r] = (float)(g * T2);
      T0 = T1; T1 = T2;
    }
  }
  return P;
}
constexpr PhiT PHI = make_phi();

// NEED[j][a]: k-subtile j (k in [32j,32j+32)) intersects Afir band of t-tile a?
// Band: rows t<100 only; s=k%100 in [t-24,t]; k<400. 53/98 true for a<7.
struct FirNeed { bool v[14][7]; };
constexpr FirNeed make_fir_need() {
  FirNeed f{};
  for (int j = 0; j < 14; ++j)
    for (int a = 0; a < 7; ++a) {
      bool need = false;
      for (int k = 32 * j; k < 32 * j + 32; ++k) {
        if (k >= 400) continue;
        int sd = k % 100;
        if (sd >= 16 * a - 24 && sd <= 16 * a + 15) need = true;
      }
      f.v[j][a] = need;
    }
  return f;
}
constexpr FirNeed FIRNEED = make_fir_need();

// 8-wide variant for the 32-col kernel (M padded to 128): a=7 covers t>=112
// (all-zero Afir rows) -> never needed. a<=6 identical to FIRNEED.
struct FirNeed8 { bool v[14][8]; };
constexpr FirNeed8 make_fir_need8() {
  FirNeed8 f{};
  for (int j = 0; j < 14; ++j)
    for (int a = 0; a < 8; ++a) {
      bool need = false;
      for (int t = 16 * a; t < 16 * a + 16 && t < 100; ++t)
        for (int k = 32 * j; k < 32 * j + 32; ++k) {
          if (k >= 400) continue;
          int sd = k % 100;
          if (sd >= t - 24 && sd <= t) need = true;
        }
      f.v[j][a] = need;
    }
  return f;
}
constexpr FirNeed8 FIRNEED8 = make_fir_need8();

__device__ __forceinline__ void gl_lds16(const void* g, void* l) {
  __builtin_amdgcn_global_load_lds(
      (const __attribute__((address_space(1))) char*)g,
      (__attribute__((address_space(3))) char*)l, 16, 0, 0);
}

// ---------------------------------------------------------------------------
// Fused setup: 3x build_wr (Chebyshev/Bessel coeffs) + build_afir + fill_xb
// (vectorized: float4 loads, 8B bf16x4 stores) + stats zero.
// ---------------------------------------------------------------------------
__device__ __forceinline__ void build_wr_body(
    const float* __restrict__ W, const float* __restrict__ P,
    __bf16* __restrict__ Wr, int CIN, int CINP, int COUT, int COUTP, int o) {
  for (int i = threadIdx.x; i < CINP; i += blockDim.x) {
    bool valid = (o < COUT) && (i < CIN);
    float w = valid ? W[(size_t)o * CIN + i] : 0.f;
    float p = valid ? P[(size_t)o * CIN + i] : 0.f;
    float S = 0.f;
#pragma unroll
    for (int l = 0; l < 25; ++l) {
      float d = ((float)(l - 12) - p) * (1.f / 12.f);
      S += expf(-0.5f * d * d);
    }
    float v = p * (1.f / 12.f);
    float g = w * expf(-0.5f * v * v) / (S + 1e-7f);
    // modified Bessel I_r(v), r = 0..3, 7-term series (|v|<=1)
    float h = 0.5f * v, hh = h * h;
    float pw = 1.f;  // h^r / r!
#pragma unroll
    for (int r = 0; r < R_RANK; ++r) {
      float term = pw, sum = pw;
#pragma unroll
      for (int m = 1; m <= 6; ++m) {
        term *= hh / (float)(m * (m + r));
        sum += term;
      }
      float c = g * ((r == 0) ? 1.f : 2.f) * sum;
      Wr[((size_t)r * COUTP + o) * CINP + i] = (__bf16)c;
      pw *= h / (float)(r + 1);
    }
  }
}

__global__ void setup_all(const float* __restrict__ x,
                          const float* __restrict__ W1, const float* __restrict__ P1,
                          const float* __restrict__ W2, const float* __restrict__ P2,
                          const float* __restrict__ W3, const float* __restrict__ P3,
                          __bf16* __restrict__ Xb, __bf16* __restrict__ Wr1,
                          __bf16* __restrict__ Wr2, __bf16* __restrict__ Wr3,
                          __bf16* __restrict__ Af, float* __restrict__ stats) {
  int blk = blockIdx.x;
  if (blk < 256) { build_wr_body(W1, P1, Wr1, 700, 704, 256, 256, blk); return; }
  blk -= 256;
  if (blk < 256) { build_wr_body(W2, P2, Wr2, 256, 256, 256, 256, blk); return; }
  blk -= 256;
  if (blk < 32) { build_wr_body(W3, P3, Wr3, 256, 256, 20, 32, blk); return; }
  blk -= 32;
  if (blk < 196) {  // Afir (112 x 448): [t][r*100+s] = PHI[s-t+24][r], else 0
    int idx = blk * 256 + threadIdx.x;
    if (idx < 112 * 448) {
      int t = idx / 448, k = idx - t * 448;
      float v = 0.f;
      if (t < 100 && k < 400) {
        int r = k / 100, s = k - r * 100;
        int tau = s - t + 24;
        if (tau >= 0 && tau < 25) v = PHI.v[tau][r];
      }
      Af[idx] = (__bf16)v;
    }
    return;
  }
  blk -= 196;
  if (blk < 2200) {  // x (B,T,700) f32 -> Xb (T,B,704) bf16, vectorized.
    int c0 = blk * 1024 + threadIdx.x;
#pragma unroll
    for (int k = 0; k < 4; ++k) {
      int c = c0 + k * 256;
      int row = c / 176, col4 = c - row * 176;
      int t = row >> 7, b = row & 127;
      uint2 pk;
      __bf16* pb = (__bf16*)&pk;
      if (col4 < 175) {
        const float* src = x + ((size_t)b * T_LEN + t) * 700 + col4 * 4;
        float4 v = *(const float4*)src;
        pb[0] = (__bf16)v.x; pb[1] = (__bf16)v.y;
        pb[2] = (__bf16)v.z; pb[3] = (__bf16)v.w;
      } else {
        pk.x = 0u; pk.y = 0u;
      }
      *(uint2*)&Xb[(size_t)row * 704 + col4 * 4] = pk;
    }
    return;
  }
  blk -= 2200;
  if (blk == 0) {
    for (int i = threadIdx.x; i < 1024; i += 256) stats[i] = 0.f;
  }
}

// ---------------------------------------------------------------------------
// Main GEMM, BK=64: Z[k=(r,t)][n=(b,o)] = A @ Wr^T. Pure async-DMA staging.
// LDS: [row][64], 8-elem kgroup slot s holds logical group s^(row&7).
// ---------------------------------------------------------------------------
template <int CINP, int BLK_N, int WROWS, int WCOLS, int CO_SH>
__global__ __launch_bounds__(256, 2)
void gemm_rk64(const __bf16* __restrict__ A, const __bf16* __restrict__ Bm,
               __bf16* __restrict__ Z) {
  constexpr int COUTP = 1 << CO_SH;
  constexpr int WM = 128 / WROWS;
  constexpr int WN = BLK_N / WCOLS;
  constexpr int RM = WM / 16;
  constexpr int RN = WN / 16;
  __shared__ __align__(16) __bf16 sA[128 * 64];
  __shared__ __align__(16) __bf16 sB[BLK_N * 64];

  const int tid = threadIdx.x;
  const int w = tid >> 6, lane = tid & 63;
  const int q = lane >> 4, ln = lane & 15;
  const int wrow = w / WCOLS, wcol = w % WCOLS;
  const int srow8 = lane >> 3;
  const int s8 = lane & 7;

  const int t0 = blockIdx.x;
  const int oc = blockIdx.y * BLK_N;
  const __bf16* Abase = A + (size_t)t0 * 128 * CINP;
  const __bf16* Bbase = Bm + (size_t)oc * CINP;

  v4f acc[RM][RN];
#pragma unroll
  for (int a = 0; a < RM; ++a)
#pragma unroll
    for (int b = 0; b < RN; ++b) acc[a][b] = v4f{0.f, 0.f, 0.f, 0.f};

  for (int ic = 0; ic < CINP; ic += 64) {
    for (int j = w; j < 16; j += 4) {  // A: 128 rows, 8 rows/issue
      int m = j * 8 + srow8;
      int g = s8 ^ (m & 7);
      gl_lds16(Abase + (size_t)m * CINP + ic + g * 8, &sA[j * 512]);
    }
    for (int j = w; j < BLK_N / 8; j += 4) {  // B
      int n = j * 8 + srow8;
      int g = s8 ^ (n & 7);
      gl_lds16(Bbase + (size_t)n * CINP + ic + g * 8, &sB[j * 512]);
    }
    __syncthreads();

#pragma unroll
    for (int s = 0; s < 2; ++s) {
      v8bf af[RM], bfr[RN];
#pragma unroll
      for (int a = 0; a < RM; ++a) {
        int m = wrow * WM + a * 16 + ln;
        af[a] = *(const v8bf*)&sA[m * 64 + ((((s << 2) | q) ^ (m & 7)) * 8)];
      }
#pragma unroll
      for (int b = 0; b < RN; ++b) {
        int n = wcol * WN + b * 16 + ln;
        bfr[b] = *(const v8bf*)&sB[n * 64 + ((((s << 2) | q) ^ (n & 7)) * 8)];
      }
#pragma unroll
      for (int a = 0; a < RM; ++a)
#pragma unroll
        for (int b = 0; b < RN; ++b)
          acc[a][b] = __builtin_amdgcn_mfma_f32_16x16x32_bf16(af[a], bfr[b], acc[a][b], 0, 0, 0);
    }
    __syncthreads();
  }

  // C/D: col=lane&15, row=quad*4+reg (m89-verified)
#pragma unroll
  for (int a = 0; a < RM; ++a) {
#pragma unroll
    for (int b = 0; b < RN; ++b) {
      int n = oc + wcol * WN + b * 16 + ln;
      int r = n >> CO_SH, o = n & (COUTP - 1);
#pragma unroll
      for (int rr = 0; rr < 4; ++rr) {
        int m = t0 * 128 + wrow * WM + a * 16 + q * 4 + rr;
        Z[((size_t)r * M_ROWS + m) * COUTP + o] = (__bf16)acc[a][b][rr];
      }
    }
  }
}

// ---------------------------------------------------------------------------
// FIR GEMM, 32-col blocks (layers 1/2): Y(112 x 32-slice) = Afir @ Z-slice.
// Grid 1024, lb(256,4), LDS 2x18816=37632B -> 4 blocks/CU = 16 waves/CU
// (2x the 64-col version's TLP; fir measured latency-bound, R17).
// Wave (mh,nh) = (w>>1, w&1) owns M-half x 16-col subtile; M padded to 8
// a-tiles, a=7 all-skip via FIRNEED8. Band guards constant-fold (templated
// MH + full unroll). Counted-wait dbuf pipeline as R13.
// ---------------------------------------------------------------------------
template <int MH>
__device__ __forceinline__ void fir32_comp(const __bf16* sA, const uint32* sBu,
                                           v4f acc[4], int i, int nh, int q, int ln) {
#pragma unroll
  for (int s = 0; s < 2; ++s) {
    int base = (nh * 16 + ln) * 35 + s * 16 + q * 4;
    uint32 tmp[4] = {sBu[base], sBu[base + 1], sBu[base + 2], sBu[base + 3]};
    v8bf bfr = *(const v8bf*)tmp;
#pragma unroll
    for (int a = 0; a < 4; ++a) {
      if (FIRNEED8.v[2 * i + s][MH * 4 + a]) {
        int m = (MH * 4 + a) * 16 + ln;
        v8bf af = *(const v8bf*)&sA[m * 64 + ((((s << 2) | q) ^ (m & 7)) * 8)];
        acc[a] = __builtin_amdgcn_mfma_f32_16x16x32_bf16(af, bfr, acc[a], 0, 0, 0);
      }
    }
  }
}

template <int COUTP>
__global__ __launch_bounds__(256, 4)
void fir_gemm32(const __bf16* __restrict__ Af, const __bf16* __restrict__ Z,
                __bf16* __restrict__ Yout, float* __restrict__ stats, int N) {
  __shared__ __align__(16) unsigned char smem[37632];  // 2 x (14336 + 4480)

  const int tid = threadIdx.x;
  const int w = tid >> 6, lane = tid & 63;
  const int q = lane >> 4, ln = lane & 15;
  const int srow8 = lane >> 3, s8 = lane & 7;
  const int kp = tid >> 3;    // 0..31 k-pairs
  const int noct = tid & 7;   // 0..7 col-quads (4 cols)
  const int mh = w >> 1, nh = w & 1;
  const int nb = blockIdx.x * 32;

  v4f acc[4];
#pragma unroll
  for (int a = 0; a < 4; ++a) acc[a] = v4f{0.f, 0.f, 0.f, 0.f};

  uint2 r0, r1;  // B-regs (row 2kp / 2kp+1, 4 cols)

#define SA32(b) ((__bf16*)(smem + (b) * 18816))
#define SB32(b) ((uint32*)(smem + (b) * 18816 + 14336))

  {  // prologue: issue tile 0
    __bf16* sA = SA32(0);
    for (int j = w; j < 14; j += 4) {
      int m = j * 8 + srow8;
      int g = s8 ^ (m & 7);
      gl_lds16(Af + (size_t)m * K_FIR + 0 + g * 8, &sA[j * 512]);
    }
    const __bf16* zp = Z + (size_t)(kp * 2) * N + nb + noct * 4;
    r0 = *(const uint2*)zp;
    r1 = *(const uint2*)(zp + N);
  }

#pragma unroll
  for (int i = 0; i < 7; ++i) {
    const int cb = i & 1;
    asm volatile("s_waitcnt vmcnt(0)" ::: "memory");
    {  // write B(i) -> LDS (transposed, k-pair packed, [col][35-dword])
      uint32* sBu = SB32(cb);
      const ushort_t* p0 = (const ushort_t*)&r0;
      const ushort_t* p1 = (const ushort_t*)&r1;
#pragma unroll
      for (int j = 0; j < 4; ++j) {
        uint32 val = (uint32)p0[j] | ((uint32)p1[j] << 16);
        sBu[(noct * 4 + j) * 35 + kp] = val;
      }
    }
    if (i < 6) {  // issue tile i+1 (in flight across compute(i))
      int kc = (i + 1) * 64;
      __bf16* sA = SA32(cb ^ 1);
      for (int j = w; j < 14; j += 4) {
        int m = j * 8 + srow8;
        int g = s8 ^ (m & 7);
        gl_lds16(Af + (size_t)m * K_FIR + kc + g * 8, &sA[j * 512]);
      }
      const __bf16* zp = Z + (size_t)(kc + kp * 2) * N + nb + noct * 4;
      r0 = *(const uint2*)zp;
      r1 = *(const uint2*)(zp + N);
    }
    asm volatile("s_waitcnt lgkmcnt(0)" ::: "memory");
    __builtin_amdgcn_s_barrier();

    if (mh == 0) fir32_comp<0>(SA32(cb), SB32(cb), acc, i, nh, q, ln);
    else         fir32_comp<1>(SA32(cb), SB32(cb), acc, i, nh, q, ln);

    __builtin_amdgcn_s_barrier();
  }

  int ng = nb + nh * 16 + ln;
  float s = 0.f, ss = 0.f;
#pragma unroll
  for (int a = 0; a < 4; ++a) {
    int am = mh * 4 + a;
#pragma unroll
    for (int rr = 0; rr < 4; ++rr) {
      int t = am * 16 + q * 4 + rr;
      float v = acc[a][rr];
      if (t < 100) {
        Yout[(size_t)t * N + ng] = (__bf16)v;
        s += v; ss += v * v;
      }
    }
  }
  // per-column sums over this wave's t-range (q-groups), then atomics
  s += __shfl_xor(s, 16); ss += __shfl_xor(ss, 16);
  s += __shfl_xor(s, 32); ss += __shfl_xor(ss, 32);
  if (q == 0) {
    int o = ng & (COUTP - 1);
    atomicAdd(&stats[o], s);
    atomicAdd(&stats[COUTP + o], ss);
  }
#undef SA32
#undef SB32
}

// ---------------------------------------------------------------------------
// FIR GEMM, 64-col (layer 3 / SOFTMAX only). R17-exact, band-skip enabled.
// ---------------------------------------------------------------------------
template <int COUTP, bool STATS, bool SOFTMAX>
__global__ __launch_bounds__(256, 2)
void fir_gemm64(const __bf16* __restrict__ Af, const __bf16* __restrict__ Z,
                __bf16* __restrict__ Yout, float* __restrict__ stats,
                float* __restrict__ outp, int N) {
  __shared__ __align__(16) unsigned char smem[46592];  // 2 x (14336 + 8960)

  const int tid = threadIdx.x;
  const int w = tid >> 6, lane = tid & 63;
  const int q = lane >> 4, ln = lane & 15;
  const int srow8 = lane >> 3, s8 = lane & 7;
  const int kp = tid >> 3;    // 0..31
  const int noct = tid & 7;   // 0..7
  const int nb = blockIdx.x * 64;

  v4f acc[7];
#pragma unroll
  for (int a = 0; a < 7; ++a) acc[a] = v4f{0.f, 0.f, 0.f, 0.f};

  uint4 r0, r1;

#define SA_BUF(b) ((__bf16*)(smem + (b) * 23296))
#define SB_BUF(b) ((uint32*)(smem + (b) * 23296 + 14336))

  {  // prologue: issue tile 0
    __bf16* sA = SA_BUF(0);
    for (int j = w; j < 14; j += 4) {
      int m = j * 8 + srow8;
      int g = s8 ^ (m & 7);
      gl_lds16(Af + (size_t)m * K_FIR + 0 + g * 8, &sA[j * 512]);
    }
    const __bf16* zp = Z + (size_t)(0 + kp * 2) * N + nb + noct * 8;
    r0 = *(const uint4*)zp;
    r1 = *(const uint4*)(zp + N);
  }

#pragma unroll
  for (int i = 0; i < 7; ++i) {
    const int cb = i & 1;
    asm volatile("s_waitcnt vmcnt(0)" ::: "memory");
    {
      uint32* sBu = SB_BUF(cb);
      const ushort_t* p0 = (const ushort_t*)&r0;
      const ushort_t* p1 = (const ushort_t*)&r1;
#pragma unroll
      for (int j = 0; j < 8; ++j) {
        uint32 val = (uint32)p0[j] | ((uint32)p1[j] << 16);
        sBu[(noct * 8 + j) * 35 + kp] = val;
      }
    }
    if (i < 6) {
      int kc = (i + 1) * 64;
      __bf16* sA = SA_BUF(cb ^ 1);
      for (int j = w; j < 14; j += 4) {
        int m = j * 8 + srow8;
        int g = s8 ^ (m & 7);
        gl_lds16(Af + (size_t)m * K_FIR + kc + g * 8, &sA[j * 512]);
      }
      const __bf16* zp = Z + (size_t)(kc + kp * 2) * N + nb + noct * 8;
      r0 = *(const uint4*)zp;
      r1 = *(const uint4*)(zp + N);
    }
    asm volatile("s_waitcnt lgkmcnt(0)" ::: "memory");
    __builtin_amdgcn_s_barrier();

    {
      __bf16* sA = SA_BUF(cb);
      uint32* sBu = SB_BUF(cb);
#pragma unroll
      for (int s = 0; s < 2; ++s) {
        v8bf af[7];
#pragma unroll
        for (int a = 0; a < 7; ++a) {
          if (FIRNEED.v[2 * i + s][a]) {
            int m = a * 16 + ln;
            af[a] = *(const v8bf*)&sA[m * 64 + ((((s << 2) | q) ^ (m & 7)) * 8)];
          }
        }
        int base = (w * 16 + ln) * 35 + s * 16 + q * 4;
        uint32 tmp[4] = {sBu[base], sBu[base + 1], sBu[base + 2], sBu[base + 3]};
        v8bf bfr = *(const v8bf*)tmp;
#pragma unroll
        for (int a = 0; a < 7; ++a) {
          if (FIRNEED.v[2 * i + s][a])
            acc[a] = __builtin_amdgcn_mfma_f32_16x16x32_bf16(af[a], bfr, acc[a], 0, 0, 0);
        }
      }
    }
    __builtin_amdgcn_s_barrier();
  }

  int ng = nb + w * 16 + ln;
  if (!SOFTMAX) {
    float s = 0.f, ss = 0.f;
#pragma unroll
    for (int a = 0; a < 7; ++a) {
#pragma unroll
      for (int rr = 0; rr < 4; ++rr) {
        int t = a * 16 + q * 4 + rr;
        float v = acc[a][rr];
        if (t < 100) {
          Yout[(size_t)t * N + ng] = (__bf16)v;
          s += v; ss += v * v;
        }
      }
    }
    if (STATS) {
      s += __shfl_xor(s, 16); ss += __shfl_xor(ss, 16);
      s += __shfl_xor(s, 32); ss += __shfl_xor(ss, 32);
      if (q == 0) {
        int o = ng & (COUTP - 1);
        atomicAdd(&stats[o], s);
        atomicAdd(&stats[COUTP + o], ss);
      }
    }
  } else {
    // L3: this block holds all t and all o for 2 batch entries.
    float* smx = (float*)smem;               // [100][65] = 26000 B (reuses bufs)
    float* lacc = (float*)(smem + 26000);    // 40 floats
    int col = w * 16 + ln;
#pragma unroll
    for (int a = 0; a < 7; ++a) {
#pragma unroll
      for (int rr = 0; rr < 4; ++rr) {
        int t = a * 16 + q * 4 + rr;
        if (t < 100) smx[t * 65 + col] = acc[a][rr];
      }
    }
    if (tid < 64) lacc[tid & 63] = 0.f;
    __syncthreads();
    if (tid < 200) {
      int bl = tid / 100, t = tid - bl * 100;
      const float* rr = &smx[t * 65 + bl * 32];
      float v[20], m = -1e30f;
#pragma unroll
      for (int o = 0; o < 20; ++o) { v[o] = rr[o]; m = fmaxf(m, v[o]); }
      float sum = 0.f;
#pragma unroll
      for (int o = 0; o < 20; ++o) { v[o] = expf(v[o] - m); sum += v[o]; }
      float inv = 1.f / sum;
#pragma unroll
      for (int o = 0; o < 20; ++o) atomicAdd(&lacc[bl * 20 + o], v[o] * inv);
    }
    __syncthreads();
    if (tid < 40) {
      int bl = tid / 20, o = tid - bl * 20;
      int b = (nb >> 5) + bl;
      outp[b * 20 + o] = lacc[bl * 20 + o];
    }
  }
#undef SA_BUF
#undef SB_BUF
}

// normalize + relu, bf16x8 vectorized, in-place on Y
__global__ __launch_bounds__(256)
void bn_apply_relu8(__bf16* __restrict__ h, const float* __restrict__ stats,
                    const float* __restrict__ gamma, const float* __restrict__ beta) {
  int idx = blockIdx.x * 256 + threadIdx.x;
  int co = (idx & 31) * 8;
  size_t row = (size_t)(idx >> 5);
  __bf16* p = h + row * 256 + co;
  uint4 raw = *(const uint4*)p;
  const ushort_t* pr = (const ushort_t*)&raw;
  uint4 outv;
  ushort_t* po = (ushort_t*)&outv;
#pragma unroll
  for (int j = 0; j < 8; ++j) {
    int c = co + j;
    float mean = stats[c] * (1.f / 12800.f);
    float var = stats[256 + c] * (1.f / 12800.f) - mean * mean;
    float inv = rsqrtf(var + 1e-5f) * gamma[c];
    uint32 u = (uint32)pr[j] << 16;
    float xv; __builtin_memcpy(&xv, &u, 4);
    float v = (xv - mean) * inv + beta[c];
    v = fmaxf(v, 0.f);
    __bf16 bv = (__bf16)v;
    po[j] = *(const ushort_t*)&bv;
  }
  *(uint4*)p = outv;
}

// ---------------------------------------------------------------------------

extern "C" void kernel_launch(void* const* d_in, const int* in_sizes, int n_in,
                              void* d_out, int out_size, void* d_ws, size_t ws_size,
                              hipStream_t stream) {
  const float* x  = (const float*)d_in[0];
  const float* W1 = (const float*)d_in[1];
  const float* P1 = (const float*)d_in[2];
  const float* W2 = (const float*)d_in[3];
  const float* P2 = (const float*)d_in[4];
  const float* W3 = (const float*)d_in[5];
  const float* P3 = (const float*)d_in[6];
  const float* g1 = (const float*)d_in[7];
  const float* b1 = (const float*)d_in[8];
  const float* g2 = (const float*)d_in[9];
  const float* b2 = (const float*)d_in[10];
  float* out = (float*)d_out;

  constexpr size_t XB_B  = (size_t)M_ROWS * 704 * 2;        // 18,022,400
  constexpr size_t Z_B   = (size_t)K_FIR * 32768 * 2;       // 29,360,128
  constexpr size_t Y12_B = (size_t)M_ROWS * 256 * 2;        //  6,553,600
  constexpr size_t W1_B  = (size_t)R_RANK * 256 * 704 * 2;  //  1,441,792
  constexpr size_t W2_B  = (size_t)R_RANK * 256 * 256 * 2;  //    524,288
  constexpr size_t W3_B  = (size_t)R_RANK * 32 * 256 * 2;   //     65,536
  constexpr size_t AF_B  = (size_t)112 * K_FIR * 2;         //    100,352
  constexpr size_t ST_B  = 4096;
  constexpr size_t TOTAL = XB_B + Z_B + Y12_B + W1_B + W2_B + W3_B + AF_B + ST_B;
  if (ws_size < TOTAL) return;

  char* ws = (char*)d_ws;
  size_t off = 0;
  __bf16* Xb   = (__bf16*)(ws + off); off += XB_B;
  __bf16* Zb   = (__bf16*)(ws + off); off += Z_B;
  __bf16* Yb   = (__bf16*)(ws + off); off += Y12_B;   // Y1 then Y2 (in-place BN)
  __bf16* Wr1  = (__bf16*)(ws + off); off += W1_B;
  __bf16* Wr2  = (__bf16*)(ws + off); off += W2_B;
  __bf16* Wr3  = (__bf16*)(ws + off); off += W3_B;
  __bf16* Afir = (__bf16*)(ws + off); off += AF_B;
  float*  stats1 = (float*)(ws + off);
  float*  stats2 = stats1 + 512;

  // fused setup: 256+256+32+196+2200+1 blocks
  setup_all<<<dim3(2941), 256, 0, stream>>>(x, W1, P1, W2, P2, W3, P3,
                                            Xb, Wr1, Wr2, Wr3, Afir, stats1);

  // layer 1: GEMM (12800 x 1024 x 704), BLK_N=256 -> FIR (+stats) -> BN in-place
  gemm_rk64<704, 256, 2, 2, 8><<<dim3(100, 4), 256, 0, stream>>>(Xb, Wr1, Zb);
  fir_gemm32<256><<<dim3(1024), 256, 0, stream>>>(Afir, Zb, Yb, stats1, 32768);
  bn_apply_relu8<<<dim3(1600), 256, 0, stream>>>(Yb, stats1, g1, b1);

  // layer 2: GEMM (12800 x 1024 x 256), BLK_N=256
  gemm_rk64<256, 256, 2, 2, 8><<<dim3(100, 4), 256, 0, stream>>>(Yb, Wr2, Zb);
  fir_gemm32<256><<<dim3(1024), 256, 0, stream>>>(Afir, Zb, Yb, stats2, 32768);
  bn_apply_relu8<<<dim3(1600), 256, 0, stream>>>(Yb, stats2, g2, b2);

  // layer 3: GEMM (12800 x 128 x 256), then FIR + fused softmax/time-sum
  gemm_rk64<256, 64, 2, 2, 5><<<dim3(100, 2), 256, 0, stream>>>(Yb, Wr3, Zb);
  fir_gemm64<32, false, true><<<dim3(64), 256, 0, stream>>>(
      Afir, Zb, nullptr, nullptr, out, 4096);
}

// Round 9
// 195.895 us; speedup vs baseline: 1.0250x; 1.0250x over previous
//
#include <hip/hip_runtime.h>
#include <stdint.h>

// ---------------------------------------------------------------------------
// d128snn_delays, round 19 = R17 fir revert (fir32 was +16.5us: per-block
// Afir staging is a FIXED cost -- splitting blocks doubled aggregate staging
// + narrowed B loads; 64-col is right) + gemm full-prefetch pipeline done
// RIGHT (R13 pattern: issue ALL of tile i+1 before a COUNTED wait on tile i;
// dbuf BOTH streams; BLK_N 256->128 keeps LDS=64KB -> 2 blocks/CU, and
// grid 800 fixes 400-block CU imbalance).
// Measured-dead-end ledger:
//   - inline BN in GEMM staging (R6): +VALU in K-loop critical path, net -.
//   - cooperative mega-kernel (R9): grid.sync() ~110us each on gfx950 -> 5x.
//   - XCD-aware swizzle (R10): serializes A-fill through one XCD's L2. -10us.
//   - R12 device-scope semaphore BN fusion: +55us PER SYNC. Never again.
//   - R14 gemm dbuf-B HALF-pipeline (A synchronous): no latency hidden. Neg.
//   - R14/R15 fir poison-mask in prefetch path: ~+5us. MFMA-skip != load-skip.
//   - R18 fir 32-col split: +16.5us. Fixed per-block staging doubled.
// R17 = best = 184.3us (band-skip fir64, 53/98 MFMAs).
// Same-code noise band: +-2.5us. Accept threshold: >3us.
// ---------------------------------------------------------------------------

#define T_LEN 100
#define B_SZ  128
#define M_ROWS 12800
#define R_RANK 4
#define K_FIR 448

typedef __bf16 v8bf __attribute__((ext_vector_type(8)));
typedef float  v4f  __attribute__((ext_vector_type(4)));
typedef unsigned int uint32;
typedef unsigned short ushort_t;

// PHI[tau][r] = exp(-u^2/2) * T_r(u), u = (tau-12)/12  (Chebyshev basis)
struct PhiT { float v[25][R_RANK]; };
constexpr double cexp_(double x) {
  double s = 1.0, t = 1.0;
  for (int n = 1; n < 30; ++n) { t = t * x / n; s += t; }
  return s;
}
constexpr PhiT make_phi() {
  PhiT P{};
  for (int tau = 0; tau < 25; ++tau) {
    double u = (tau - 12) / 12.0;
    double g = cexp_(-0.5 * u * u);
    double T0 = 1.0, T1 = u;
    P.v[tau][0] = (float)(g * T0);
    P.v[tau][1] = (float)(g * T1);
    for (int r = 2; r < R_RANK; ++r) {
      double T2 = 2.0 * u * T1 - T0;
      P.v[tau][r] = (float)(g * T2);
      T0 = T1; T1 = T2;
    }
  }
  return P;
}
constexpr PhiT PHI = make_phi();

// NEED[j][a]: k-subtile j (k in [32j,32j+32)) intersects Afir band of t-tile a?
// Band: rows t<100 only; s=k%100 in [t-24,t]; k<400. 53/98 true.
struct FirNeed { bool v[14][7]; };
constexpr FirNeed make_fir_need() {
  FirNeed f{};
  for (int j = 0; j < 14; ++j)
    for (int a = 0; a < 7; ++a) {
      bool need = false;
      for (int k = 32 * j; k < 32 * j + 32; ++k) {
        if (k >= 400) continue;
        int sd = k % 100;
        if (sd >= 16 * a - 24 && sd <= 16 * a + 15) need = true;
      }
      f.v[j][a] = need;
    }
  return f;
}
constexpr FirNeed FIRNEED = make_fir_need();

__device__ __forceinline__ void gl_lds16(const void* g, void* l) {
  __builtin_amdgcn_global_load_lds(
      (const __attribute__((address_space(1))) char*)g,
      (__attribute__((address_space(3))) char*)l, 16, 0, 0);
}

// ---------------------------------------------------------------------------
// Fused setup: 3x build_wr (Chebyshev/Bessel coeffs) + build_afir + fill_xb
// (vectorized: float4 loads, 8B bf16x4 stores) + stats zero.
// ---------------------------------------------------------------------------
__device__ __forceinline__ void build_wr_body(
    const float* __restrict__ W, const float* __restrict__ P,
    __bf16* __restrict__ Wr, int CIN, int CINP, int COUT, int COUTP, int o) {
  for (int i = threadIdx.x; i < CINP; i += blockDim.x) {
    bool valid = (o < COUT) && (i < CIN);
    float w = valid ? W[(size_t)o * CIN + i] : 0.f;
    float p = valid ? P[(size_t)o * CIN + i] : 0.f;
    float S = 0.f;
#pragma unroll
    for (int l = 0; l < 25; ++l) {
      float d = ((float)(l - 12) - p) * (1.f / 12.f);
      S += expf(-0.5f * d * d);
    }
    float v = p * (1.f / 12.f);
    float g = w * expf(-0.5f * v * v) / (S + 1e-7f);
    // modified Bessel I_r(v), r = 0..3, 7-term series (|v|<=1)
    float h = 0.5f * v, hh = h * h;
    float pw = 1.f;  // h^r / r!
#pragma unroll
    for (int r = 0; r < R_RANK; ++r) {
      float term = pw, sum = pw;
#pragma unroll
      for (int m = 1; m <= 6; ++m) {
        term *= hh / (float)(m * (m + r));
        sum += term;
      }
      float c = g * ((r == 0) ? 1.f : 2.f) * sum;
      Wr[((size_t)r * COUTP + o) * CINP + i] = (__bf16)c;
      pw *= h / (float)(r + 1);
    }
  }
}

__global__ void setup_all(const float* __restrict__ x,
                          const float* __restrict__ W1, const float* __restrict__ P1,
                          const float* __restrict__ W2, const float* __restrict__ P2,
                          const float* __restrict__ W3, const float* __restrict__ P3,
                          __bf16* __restrict__ Xb, __bf16* __restrict__ Wr1,
                          __bf16* __restrict__ Wr2, __bf16* __restrict__ Wr3,
                          __bf16* __restrict__ Af, float* __restrict__ stats) {
  int blk = blockIdx.x;
  if (blk < 256) { build_wr_body(W1, P1, Wr1, 700, 704, 256, 256, blk); return; }
  blk -= 256;
  if (blk < 256) { build_wr_body(W2, P2, Wr2, 256, 256, 256, 256, blk); return; }
  blk -= 256;
  if (blk < 32) { build_wr_body(W3, P3, Wr3, 256, 256, 20, 32, blk); return; }
  blk -= 32;
  if (blk < 196) {  // Afir (112 x 448): [t][r*100+s] = PHI[s-t+24][r], else 0
    int idx = blk * 256 + threadIdx.x;
    if (idx < 112 * 448) {
      int t = idx / 448, k = idx - t * 448;
      float v = 0.f;
      if (t < 100 && k < 400) {
        int r = k / 100, s = k - r * 100;
        int tau = s - t + 24;
        if (tau >= 0 && tau < 25) v = PHI.v[tau][r];
      }
      Af[idx] = (__bf16)v;
    }
    return;
  }
  blk -= 196;
  if (blk < 2200) {  // x (B,T,700) f32 -> Xb (T,B,704) bf16, vectorized.
    int c0 = blk * 1024 + threadIdx.x;
#pragma unroll
    for (int k = 0; k < 4; ++k) {
      int c = c0 + k * 256;
      int row = c / 176, col4 = c - row * 176;
      int t = row >> 7, b = row & 127;
      uint2 pk;
      __bf16* pb = (__bf16*)&pk;
      if (col4 < 175) {
        const float* src = x + ((size_t)b * T_LEN + t) * 700 + col4 * 4;
        float4 v = *(const float4*)src;
        pb[0] = (__bf16)v.x; pb[1] = (__bf16)v.y;
        pb[2] = (__bf16)v.z; pb[3] = (__bf16)v.w;
      } else {
        pk.x = 0u; pk.y = 0u;
      }
      *(uint2*)&Xb[(size_t)row * 704 + col4 * 4] = pk;
    }
    return;
  }
  blk -= 2200;
  if (blk == 0) {
    for (int i = threadIdx.x; i < 1024; i += 256) stats[i] = 0.f;
  }
}

// ---------------------------------------------------------------------------
// Main GEMM, BK=64, FULL-prefetch pipeline (R13-proven pattern):
// both sA and sB double-buffered; loop = { issue tile i+1 (A+B, all DMAs)
// -> counted vmcnt (drain tile i only, tile i+1 stays in flight) -> barrier
// -> MFMA(buf i) -> barrier }. Tile i+1's latency hides under compute(i).
// BLK_N=128: LDS 64KB -> 2 blocks/CU kept; grid (100,8)=800 blocks balances
// all 256 CUs (old 400-block grid left 112 block-slots empty).
// ---------------------------------------------------------------------------
template <int CINP, int BLK_N, int WROWS, int WCOLS, int CO_SH>
__global__ __launch_bounds__(256, 2)
void gemm_rk64(const __bf16* __restrict__ A, const __bf16* __restrict__ Bm,
               __bf16* __restrict__ Z) {
  constexpr int COUTP = 1 << CO_SH;
  constexpr int WM = 128 / WROWS;
  constexpr int WN = BLK_N / WCOLS;
  constexpr int RM = WM / 16;
  constexpr int RN = WN / 16;
  constexpr int NITER = CINP / 64;
  __shared__ __align__(16) __bf16 sA[2][128 * 64];
  __shared__ __align__(16) __bf16 sB[2][BLK_N * 64];

  const int tid = threadIdx.x;
  const int w = tid >> 6, lane = tid & 63;
  const int q = lane >> 4, ln = lane & 15;
  const int wrow = w / WCOLS, wcol = w % WCOLS;
  const int srow8 = lane >> 3;
  const int s8 = lane & 7;

  const int t0 = blockIdx.x;
  const int oc = blockIdx.y * BLK_N;
  const __bf16* Abase = A + (size_t)t0 * 128 * CINP;
  const __bf16* Bbase = Bm + (size_t)oc * CINP;

  v4f acc[RM][RN];
#pragma unroll
  for (int a = 0; a < RM; ++a)
#pragma unroll
    for (int b = 0; b < RN; ++b) acc[a][b] = v4f{0.f, 0.f, 0.f, 0.f};

  // stage tile `it` into buffer `bf` (all A + B DMAs; 4 + BLK_N/32 per thread)
  auto stage = [&](int it, int bf) {
    const int ic = it * 64;
    for (int j = w; j < 16; j += 4) {
      int m = j * 8 + srow8;
      int g = s8 ^ (m & 7);
      gl_lds16(Abase + (size_t)m * CINP + ic + g * 8, &sA[bf][j * 512]);
    }
    for (int j = w; j < BLK_N / 8; j += 4) {
      int n = j * 8 + srow8;
      int g = s8 ^ (n & 7);
      gl_lds16(Bbase + (size_t)n * CINP + ic + g * 8, &sB[bf][j * 512]);
    }
  };

  stage(0, 0);  // prologue

  for (int i = 0; i < NITER; ++i) {
    if (i + 1 < NITER) {
      stage(i + 1, (i + 1) & 1);  // issue BEFORE the wait (full pipeline)
      // drain tile i's (4 + BLK_N/32) DMAs; leave tile i+1's in flight
      if constexpr (BLK_N == 128) {
        asm volatile("s_waitcnt vmcnt(8)" ::: "memory");
      } else if constexpr (BLK_N == 64) {
        asm volatile("s_waitcnt vmcnt(6)" ::: "memory");
      } else {
        asm volatile("s_waitcnt vmcnt(12)" ::: "memory");
      }
    } else {
      asm volatile("s_waitcnt vmcnt(0)" ::: "memory");
    }
    __builtin_amdgcn_s_barrier();

    const __bf16* sAc = sA[i & 1];
    const __bf16* sBc = sB[i & 1];
#pragma unroll
    for (int s = 0; s < 2; ++s) {
      v8bf af[RM], bfr[RN];
#pragma unroll
      for (int a = 0; a < RM; ++a) {
        int m = wrow * WM + a * 16 + ln;
        af[a] = *(const v8bf*)&sAc[m * 64 + ((((s << 2) | q) ^ (m & 7)) * 8)];
      }
#pragma unroll
      for (int b = 0; b < RN; ++b) {
        int n = wcol * WN + b * 16 + ln;
        bfr[b] = *(const v8bf*)&sBc[n * 64 + ((((s << 2) | q) ^ (n & 7)) * 8)];
      }
#pragma unroll
      for (int a = 0; a < RM; ++a)
#pragma unroll
        for (int b = 0; b < RN; ++b)
          acc[a][b] = __builtin_amdgcn_mfma_f32_16x16x32_bf16(af[a], bfr[b], acc[a][b], 0, 0, 0);
    }
    __builtin_amdgcn_s_barrier();  // readers done before buf (i+1)&1 reuse
  }

  // C/D: col=lane&15, row=quad*4+reg (m89-verified)
#pragma unroll
  for (int a = 0; a < RM; ++a) {
#pragma unroll
    for (int b = 0; b < RN; ++b) {
      int n = oc + wcol * WN + b * 16 + ln;
      int r = n >> CO_SH, o = n & (COUTP - 1);
#pragma unroll
      for (int rr = 0; rr < 4; ++rr) {
        int m = t0 * 128 + wrow * WM + a * 16 + q * 4 + rr;
        Z[((size_t)r * M_ROWS + m) * COUTP + o] = (__bf16)acc[a][b][rr];
      }
    }
  }
}

// ---------------------------------------------------------------------------
// FIR GEMM, 64-col (R17-exact): Y(112 x 64-slice) = Afir(112x448) @ Z(448xN).
// Dbuf counted-wait pipeline + constexpr band-skip (53/98 MFMAs).
// STATS: fused BN sum/sumsq atomics.  SOFTMAX (L3): in-LDS softmax + t-sum.
// ---------------------------------------------------------------------------
template <int COUTP, bool STATS, bool SOFTMAX>
__global__ __launch_bounds__(256, 2)
void fir_gemm64(const __bf16* __restrict__ Af, const __bf16* __restrict__ Z,
                __bf16* __restrict__ Yout, float* __restrict__ stats,
                float* __restrict__ outp, int N) {
  __shared__ __align__(16) unsigned char smem[46592];  // 2 x (14336 + 8960)

  const int tid = threadIdx.x;
  const int w = tid >> 6, lane = tid & 63;
  const int q = lane >> 4, ln = lane & 15;
  const int srow8 = lane >> 3, s8 = lane & 7;
  const int kp = tid >> 3;    // 0..31
  const int noct = tid & 7;   // 0..7
  const int nb = blockIdx.x * 64;

  v4f acc[7];
#pragma unroll
  for (int a = 0; a < 7; ++a) acc[a] = v4f{0.f, 0.f, 0.f, 0.f};

  uint4 r0, r1;

#define SA_BUF(b) ((__bf16*)(smem + (b) * 23296))
#define SB_BUF(b) ((uint32*)(smem + (b) * 23296 + 14336))

  {  // prologue: issue tile 0
    __bf16* sA = SA_BUF(0);
    for (int j = w; j < 14; j += 4) {
      int m = j * 8 + srow8;
      int g = s8 ^ (m & 7);
      gl_lds16(Af + (size_t)m * K_FIR + 0 + g * 8, &sA[j * 512]);
    }
    const __bf16* zp = Z + (size_t)(0 + kp * 2) * N + nb + noct * 8;
    r0 = *(const uint4*)zp;
    r1 = *(const uint4*)(zp + N);
  }

#pragma unroll
  for (int i = 0; i < 7; ++i) {
    const int cb = i & 1;
    asm volatile("s_waitcnt vmcnt(0)" ::: "memory");
    {
      uint32* sBu = SB_BUF(cb);
      const ushort_t* p0 = (const ushort_t*)&r0;
      const ushort_t* p1 = (const ushort_t*)&r1;
#pragma unroll
      for (int j = 0; j < 8; ++j) {
        uint32 val = (uint32)p0[j] | ((uint32)p1[j] << 16);
        sBu[(noct * 8 + j) * 35 + kp] = val;
      }
    }
    if (i < 6) {
      int kc = (i + 1) * 64;
      __bf16* sA = SA_BUF(cb ^ 1);
      for (int j = w; j < 14; j += 4) {
        int m = j * 8 + srow8;
        int g = s8 ^ (m & 7);
        gl_lds16(Af + (size_t)m * K_FIR + kc + g * 8, &sA[j * 512]);
      }
      const __bf16* zp = Z + (size_t)(kc + kp * 2) * N + nb + noct * 8;
      r0 = *(const uint4*)zp;
      r1 = *(const uint4*)(zp + N);
    }
    asm volatile("s_waitcnt lgkmcnt(0)" ::: "memory");
    __builtin_amdgcn_s_barrier();

    {
      __bf16* sA = SA_BUF(cb);
      uint32* sBu = SB_BUF(cb);
#pragma unroll
      for (int s = 0; s < 2; ++s) {
        v8bf af[7];
#pragma unroll
        for (int a = 0; a < 7; ++a) {
          if (FIRNEED.v[2 * i + s][a]) {
            int m = a * 16 + ln;
            af[a] = *(const v8bf*)&sA[m * 64 + ((((s << 2) | q) ^ (m & 7)) * 8)];
          }
        }
        int base = (w * 16 + ln) * 35 + s * 16 + q * 4;
        uint32 tmp[4] = {sBu[base], sBu[base + 1], sBu[base + 2], sBu[base + 3]};
        v8bf bfr = *(const v8bf*)tmp;
#pragma unroll
        for (int a = 0; a < 7; ++a) {
          if (FIRNEED.v[2 * i + s][a])
            acc[a] = __builtin_amdgcn_mfma_f32_16x16x32_bf16(af[a], bfr, acc[a], 0, 0, 0);
        }
      }
    }
    __builtin_amdgcn_s_barrier();
  }

  int ng = nb + w * 16 + ln;
  if (!SOFTMAX) {
    float s = 0.f, ss = 0.f;
#pragma unroll
    for (int a = 0; a < 7; ++a) {
#pragma unroll
      for (int rr = 0; rr < 4; ++rr) {
        int t = a * 16 + q * 4 + rr;
        float v = acc[a][rr];
        if (t < 100) {
          Yout[(size_t)t * N + ng] = (__bf16)v;
          s += v; ss += v * v;
        }
      }
    }
    if (STATS) {
      s += __shfl_xor(s, 16); ss += __shfl_xor(ss, 16);
      s += __shfl_xor(s, 32); ss += __shfl_xor(ss, 32);
      if (q == 0) {
        int o = ng & (COUTP - 1);
        atomicAdd(&stats[o], s);
        atomicAdd(&stats[COUTP + o], ss);
      }
    }
  } else {
    // L3: this block holds all t and all o for 2 batch entries.
    float* smx = (float*)smem;               // [100][65] = 26000 B (reuses bufs)
    float* lacc = (float*)(smem + 26000);    // 40 floats
    int col = w * 16 + ln;
#pragma unroll
    for (int a = 0; a < 7; ++a) {
#pragma unroll
      for (int rr = 0; rr < 4; ++rr) {
        int t = a * 16 + q * 4 + rr;
        if (t < 100) smx[t * 65 + col] = acc[a][rr];
      }
    }
    if (tid < 64) lacc[tid & 63] = 0.f;
    __syncthreads();
    if (tid < 200) {
      int bl = tid / 100, t = tid - bl * 100;
      const float* rr = &smx[t * 65 + bl * 32];
      float v[20], m = -1e30f;
#pragma unroll
      for (int o = 0; o < 20; ++o) { v[o] = rr[o]; m = fmaxf(m, v[o]); }
      float sum = 0.f;
#pragma unroll
      for (int o = 0; o < 20; ++o) { v[o] = expf(v[o] - m); sum += v[o]; }
      float inv = 1.f / sum;
#pragma unroll
      for (int o = 0; o < 20; ++o) atomicAdd(&lacc[bl * 20 + o], v[o] * inv);
    }
    __syncthreads();
    if (tid < 40) {
      int bl = tid / 20, o = tid - bl * 20;
      int b = (nb >> 5) + bl;
      outp[b * 20 + o] = lacc[bl * 20 + o];
    }
  }
#undef SA_BUF
#undef SB_BUF
}

// normalize + relu, bf16x8 vectorized, in-place on Y
__global__ __launch_bounds__(256)
void bn_apply_relu8(__bf16* __restrict__ h, const float* __restrict__ stats,
                    const float* __restrict__ gamma, const float* __restrict__ beta) {
  int idx = blockIdx.x * 256 + threadIdx.x;
  int co = (idx & 31) * 8;
  size_t row = (size_t)(idx >> 5);
  __bf16* p = h + row * 256 + co;
  uint4 raw = *(const uint4*)p;
  const ushort_t* pr = (const ushort_t*)&raw;
  uint4 outv;
  ushort_t* po = (ushort_t*)&outv;
#pragma unroll
  for (int j = 0; j < 8; ++j) {
    int c = co + j;
    float mean = stats[c] * (1.f / 12800.f);
    float var = stats[256 + c] * (1.f / 12800.f) - mean * mean;
    float inv = rsqrtf(var + 1e-5f) * gamma[c];
    uint32 u = (uint32)pr[j] << 16;
    float xv; __builtin_memcpy(&xv, &u, 4);
    float v = (xv - mean) * inv + beta[c];
    v = fmaxf(v, 0.f);
    __bf16 bv = (__bf16)v;
    po[j] = *(const ushort_t*)&bv;
  }
  *(uint4*)p = outv;
}

// ---------------------------------------------------------------------------

extern "C" void kernel_launch(void* const* d_in, const int* in_sizes, int n_in,
                              void* d_out, int out_size, void* d_ws, size_t ws_size,
                              hipStream_t stream) {
  const float* x  = (const float*)d_in[0];
  const float* W1 = (const float*)d_in[1];
  const float* P1 = (const float*)d_in[2];
  const float* W2 = (const float*)d_in[3];
  const float* P2 = (const float*)d_in[4];
  const float* W3 = (const float*)d_in[5];
  const float* P3 = (const float*)d_in[6];
  const float* g1 = (const float*)d_in[7];
  const float* b1 = (const float*)d_in[8];
  const float* g2 = (const float*)d_in[9];
  const float* b2 = (const float*)d_in[10];
  float* out = (float*)d_out;

  constexpr size_t XB_B  = (size_t)M_ROWS * 704 * 2;        // 18,022,400
  constexpr size_t Z_B   = (size_t)K_FIR * 32768 * 2;       // 29,360,128
  constexpr size_t Y12_B = (size_t)M_ROWS * 256 * 2;        //  6,553,600
  constexpr size_t W1_B  = (size_t)R_RANK * 256 * 704 * 2;  //  1,441,792
  constexpr size_t W2_B  = (size_t)R_RANK * 256 * 256 * 2;  //    524,288
  constexpr size_t W3_B  = (size_t)R_RANK * 32 * 256 * 2;   //     65,536
  constexpr size_t AF_B  = (size_t)112 * K_FIR * 2;         //    100,352
  constexpr size_t ST_B  = 4096;
  constexpr size_t TOTAL = XB_B + Z_B + Y12_B + W1_B + W2_B + W3_B + AF_B + ST_B;
  if (ws_size < TOTAL) return;

  char* ws = (char*)d_ws;
  size_t off = 0;
  __bf16* Xb   = (__bf16*)(ws + off); off += XB_B;
  __bf16* Zb   = (__bf16*)(ws + off); off += Z_B;
  __bf16* Yb   = (__bf16*)(ws + off); off += Y12_B;   // Y1 then Y2 (in-place BN)
  __bf16* Wr1  = (__bf16*)(ws + off); off += W1_B;
  __bf16* Wr2  = (__bf16*)(ws + off); off += W2_B;
  __bf16* Wr3  = (__bf16*)(ws + off); off += W3_B;
  __bf16* Afir = (__bf16*)(ws + off); off += AF_B;
  float*  stats1 = (float*)(ws + off);
  float*  stats2 = stats1 + 512;

  // fused setup: 256+256+32+196+2200+1 blocks
  setup_all<<<dim3(2941), 256, 0, stream>>>(x, W1, P1, W2, P2, W3, P3,
                                            Xb, Wr1, Wr2, Wr3, Afir, stats1);

  // layer 1: GEMM (12800 x 1024 x 704), BLK_N=128, full pipeline -> FIR -> BN
  gemm_rk64<704, 128, 2, 2, 8><<<dim3(100, 8), 256, 0, stream>>>(Xb, Wr1, Zb);
  fir_gemm64<256, true, false><<<dim3(512), 256, 0, stream>>>(
      Afir, Zb, Yb, stats1, nullptr, 32768);
  bn_apply_relu8<<<dim3(1600), 256, 0, stream>>>(Yb, stats1, g1, b1);

  // layer 2: GEMM (12800 x 1024 x 256), BLK_N=128
  gemm_rk64<256, 128, 2, 2, 8><<<dim3(100, 8), 256, 0, stream>>>(Yb, Wr2, Zb);
  fir_gemm64<256, true, false><<<dim3(512), 256, 0, stream>>>(
      Afir, Zb, Yb, stats2, nullptr, 32768);
  bn_apply_relu8<<<dim3(1600), 256, 0, stream>>>(Yb, stats2, g2, b2);

  // layer 3: GEMM (12800 x 128 x 256), BLK_N=64, then FIR + softmax/time-sum
  gemm_rk64<256, 64, 2, 2, 5><<<dim3(100, 2), 256, 0, stream>>>(Yb, Wr3, Zb);
  fir_gemm64<32, false, true><<<dim3(64), 256, 0, stream>>>(
      Afir, Zb, nullptr, nullptr, out, 4096);
}

// Round 10
// 186.791 us; speedup vs baseline: 1.0750x; 1.0487x over previous
//
#include <hip/hip_runtime.h>
#include <stdint.h>

// ---------------------------------------------------------------------------
// d128snn_delays, round 20 = byte-exact R17 restore (measured best: 184.3us).
// Session summary (9 rounds of A/B on this harness):
//   WINS: R13 fir counted-wait dbuf pipeline + vectorized setup (-10us);
//         R17 fir MFMA band-skip, 53/98 MFMAs via constexpr table (-2us).
//   Measured-dead-end ledger (do not retry):
//   - inline BN in GEMM staging (R6): +VALU in K-loop critical path, net -.
//   - cooperative mega-kernel / ANY grid-wide sync (R9, R12): +55us PER SYNC
//     on gfx950 (512 agent-scope pollers starve the releasing atomics).
//   - XCD-aware swizzle (R10): -10us (L3 already dedupes this working set).
//   - gemm dbuf-B half-pipeline (R14): A issued sync before wait -> nothing
//     hidden, LDS 2x. +4.5us.
//   - fir poison-row load-mask (R14/15): conditional in prefetch-issue path
//     costs more than L3-absorbed poison reads. +5us. MFMA-skip != load-skip.
//   - coalesced-Z repack epilogue (R15): neutral (Z writes L2-absorbed).
//   - fir 32-col block split for TLP (R18): per-block Afir staging is FIXED
//     cost -> aggregate staging 2x. +16.5us.
//   - gemm full-prefetch at BLK_N=128 (R19): pipeline correct but A-tile
//     staged by 2x blocks (72->144MB) + 2x per-block fixed costs. +11.6us.
//     At BLK_N=256 dbuf doesn't fit LDS (96KB > 80KB/2blk). Boxed in.
// Floor decomposition @184.3us: ~42us harness ws-poison fill (fills full
// workspace, independent of our layout) + ~45us dispatch-boundary gaps
// (9-dispatch chain is dependency-minimal; sync elimination measured worse)
// + ~97us kernels (latency-structure-bound; five counter-driven attacks all
// regressed). Same-code noise +-2.5us.
// ---------------------------------------------------------------------------

#define T_LEN 100
#define B_SZ  128
#define M_ROWS 12800
#define R_RANK 4
#define K_FIR 448

typedef __bf16 v8bf __attribute__((ext_vector_type(8)));
typedef float  v4f  __attribute__((ext_vector_type(4)));
typedef unsigned int uint32;
typedef unsigned short ushort_t;

// PHI[tau][r] = exp(-u^2/2) * T_r(u), u = (tau-12)/12  (Chebyshev basis)
struct PhiT { float v[25][R_RANK]; };
constexpr double cexp_(double x) {
  double s = 1.0, t = 1.0;
  for (int n = 1; n < 30; ++n) { t = t * x / n; s += t; }
  return s;
}
constexpr PhiT make_phi() {
  PhiT P{};
  for (int tau = 0; tau < 25; ++tau) {
    double u = (tau - 12) / 12.0;
    double g = cexp_(-0.5 * u * u);
    double T0 = 1.0, T1 = u;
    P.v[tau][0] = (float)(g * T0);
    P.v[tau][1] = (float)(g * T1);
    for (int r = 2; r < R_RANK; ++r) {
      double T2 = 2.0 * u * T1 - T0;
      P.v[tau][r] = (float)(g * T2);
      T0 = T1; T1 = T2;
    }
  }
  return P;
}
constexpr PhiT PHI = make_phi();

// NEED[j][a]: does k-subtile j (k in [32j,32j+32)) intersect the Afir band
// of t-tile a (t in [16a,16a+16), band s in [t-24,t])? 53 of 98 true.
struct FirNeed { bool v[14][7]; };
constexpr FirNeed make_fir_need() {
  FirNeed f{};
  for (int j = 0; j < 14; ++j)
    for (int a = 0; a < 7; ++a) {
      bool need = false;
      for (int k = 32 * j; k < 32 * j + 32; ++k) {
        if (k >= 400) continue;           // rows 400+: Afir zero (and poison Z)
        int sd = k % 100;
        if (sd >= 16 * a - 24 && sd <= 16 * a + 15) need = true;
      }
      f.v[j][a] = need;
    }
  return f;
}
constexpr FirNeed FIRNEED = make_fir_need();

__device__ __forceinline__ void gl_lds16(const void* g, void* l) {
  __builtin_amdgcn_global_load_lds(
      (const __attribute__((address_space(1))) char*)g,
      (__attribute__((address_space(3))) char*)l, 16, 0, 0);
}

// ---------------------------------------------------------------------------
// Fused setup: 3x build_wr (Chebyshev/Bessel coeffs) + build_afir + fill_xb
// (vectorized: float4 loads, 8B bf16x4 stores) + stats zero.
// ---------------------------------------------------------------------------
__device__ __forceinline__ void build_wr_body(
    const float* __restrict__ W, const float* __restrict__ P,
    __bf16* __restrict__ Wr, int CIN, int CINP, int COUT, int COUTP, int o) {
  for (int i = threadIdx.x; i < CINP; i += blockDim.x) {
    bool valid = (o < COUT) && (i < CIN);
    float w = valid ? W[(size_t)o * CIN + i] : 0.f;
    float p = valid ? P[(size_t)o * CIN + i] : 0.f;
    float S = 0.f;
#pragma unroll
    for (int l = 0; l < 25; ++l) {
      float d = ((float)(l - 12) - p) * (1.f / 12.f);
      S += expf(-0.5f * d * d);
    }
    float v = p * (1.f / 12.f);
    float g = w * expf(-0.5f * v * v) / (S + 1e-7f);
    // modified Bessel I_r(v), r = 0..3, 7-term series (|v|<=1)
    float h = 0.5f * v, hh = h * h;
    float pw = 1.f;  // h^r / r!
#pragma unroll
    for (int r = 0; r < R_RANK; ++r) {
      float term = pw, sum = pw;
#pragma unroll
      for (int m = 1; m <= 6; ++m) {
        term *= hh / (float)(m * (m + r));
        sum += term;
      }
      float c = g * ((r == 0) ? 1.f : 2.f) * sum;
      Wr[((size_t)r * COUTP + o) * CINP + i] = (__bf16)c;
      pw *= h / (float)(r + 1);
    }
  }
}

__global__ void setup_all(const float* __restrict__ x,
                          const float* __restrict__ W1, const float* __restrict__ P1,
                          const float* __restrict__ W2, const float* __restrict__ P2,
                          const float* __restrict__ W3, const float* __restrict__ P3,
                          __bf16* __restrict__ Xb, __bf16* __restrict__ Wr1,
                          __bf16* __restrict__ Wr2, __bf16* __restrict__ Wr3,
                          __bf16* __restrict__ Af, float* __restrict__ stats) {
  int blk = blockIdx.x;
  if (blk < 256) { build_wr_body(W1, P1, Wr1, 700, 704, 256, 256, blk); return; }
  blk -= 256;
  if (blk < 256) { build_wr_body(W2, P2, Wr2, 256, 256, 256, 256, blk); return; }
  blk -= 256;
  if (blk < 32) { build_wr_body(W3, P3, Wr3, 256, 256, 20, 32, blk); return; }
  blk -= 32;
  if (blk < 196) {  // Afir (112 x 448): [t][r*100+s] = PHI[s-t+24][r], else 0
    int idx = blk * 256 + threadIdx.x;
    if (idx < 112 * 448) {
      int t = idx / 448, k = idx - t * 448;
      float v = 0.f;
      if (t < 100 && k < 400) {
        int r = k / 100, s = k - r * 100;
        int tau = s - t + 24;
        if (tau >= 0 && tau < 25) v = PHI.v[tau][r];
      }
      Af[idx] = (__bf16)v;
    }
    return;
  }
  blk -= 196;
  if (blk < 2200) {  // x (B,T,700) f32 -> Xb (T,B,704) bf16, vectorized.
    // chunk = 4 cols; 176 chunks/row (chunk 175 = pad), 12800 rows.
    // 2200 blocks * 256 thr * 4 chunks = 2,252,800 = 12800*176 exact cover.
    int c0 = blk * 1024 + threadIdx.x;
#pragma unroll
    for (int k = 0; k < 4; ++k) {
      int c = c0 + k * 256;
      int row = c / 176, col4 = c - row * 176;
      int t = row >> 7, b = row & 127;
      uint2 pk;
      __bf16* pb = (__bf16*)&pk;
      if (col4 < 175) {
        const float* src = x + ((size_t)b * T_LEN + t) * 700 + col4 * 4;
        float4 v = *(const float4*)src;   // 16B-aligned: row base 2800B, +16B
        pb[0] = (__bf16)v.x; pb[1] = (__bf16)v.y;
        pb[2] = (__bf16)v.z; pb[3] = (__bf16)v.w;
      } else {
        pk.x = 0u; pk.y = 0u;
      }
      *(uint2*)&Xb[(size_t)row * 704 + col4 * 4] = pk;
    }
    return;
  }
  blk -= 2200;
  if (blk == 0) {
    for (int i = threadIdx.x; i < 1024; i += 256) stats[i] = 0.f;
  }
}

// ---------------------------------------------------------------------------
// Main GEMM, BK=64: Z[k=(r,t)][n=(b,o)] = A @ Wr^T. Pure async-DMA staging.
// LDS: [row][64], 8-elem kgroup slot s holds logical group s^(row&7).
// ---------------------------------------------------------------------------
template <int CINP, int BLK_N, int WROWS, int WCOLS, int CO_SH>
__global__ __launch_bounds__(256, 2)
void gemm_rk64(const __bf16* __restrict__ A, const __bf16* __restrict__ Bm,
               __bf16* __restrict__ Z) {
  constexpr int COUTP = 1 << CO_SH;
  constexpr int WM = 128 / WROWS;
  constexpr int WN = BLK_N / WCOLS;
  constexpr int RM = WM / 16;
  constexpr int RN = WN / 16;
  __shared__ __align__(16) __bf16 sA[128 * 64];
  __shared__ __align__(16) __bf16 sB[BLK_N * 64];

  const int tid = threadIdx.x;
  const int w = tid >> 6, lane = tid & 63;
  const int q = lane >> 4, ln = lane & 15;
  const int wrow = w / WCOLS, wcol = w % WCOLS;
  const int srow8 = lane >> 3;
  const int s8 = lane & 7;

  const int t0 = blockIdx.x;
  const int oc = blockIdx.y * BLK_N;
  const __bf16* Abase = A + (size_t)t0 * 128 * CINP;
  const __bf16* Bbase = Bm + (size_t)oc * CINP;

  v4f acc[RM][RN];
#pragma unroll
  for (int a = 0; a < RM; ++a)
#pragma unroll
    for (int b = 0; b < RN; ++b) acc[a][b] = v4f{0.f, 0.f, 0.f, 0.f};

  for (int ic = 0; ic < CINP; ic += 64) {
    for (int j = w; j < 16; j += 4) {  // A: 128 rows, 8 rows/issue
      int m = j * 8 + srow8;
      int g = s8 ^ (m & 7);
      gl_lds16(Abase + (size_t)m * CINP + ic + g * 8, &sA[j * 512]);
    }
    for (int j = w; j < BLK_N / 8; j += 4) {  // B
      int n = j * 8 + srow8;
      int g = s8 ^ (n & 7);
      gl_lds16(Bbase + (size_t)n * CINP + ic + g * 8, &sB[j * 512]);
    }
    __syncthreads();

#pragma unroll
    for (int s = 0; s < 2; ++s) {
      v8bf af[RM], bfr[RN];
#pragma unroll
      for (int a = 0; a < RM; ++a) {
        int m = wrow * WM + a * 16 + ln;
        af[a] = *(const v8bf*)&sA[m * 64 + ((((s << 2) | q) ^ (m & 7)) * 8)];
      }
#pragma unroll
      for (int b = 0; b < RN; ++b) {
        int n = wcol * WN + b * 16 + ln;
        bfr[b] = *(const v8bf*)&sB[n * 64 + ((((s << 2) | q) ^ (n & 7)) * 8)];
      }
#pragma unroll
      for (int a = 0; a < RM; ++a)
#pragma unroll
        for (int b = 0; b < RN; ++b)
          acc[a][b] = __builtin_amdgcn_mfma_f32_16x16x32_bf16(af[a], bfr[b], acc[a][b], 0, 0, 0);
    }
    __syncthreads();
  }

  // C/D: col=lane&15, row=quad*4+reg (m89-verified)
#pragma unroll
  for (int a = 0; a < RM; ++a) {
#pragma unroll
    for (int b = 0; b < RN; ++b) {
      int n = oc + wcol * WN + b * 16 + ln;
      int r = n >> CO_SH, o = n & (COUTP - 1);
#pragma unroll
      for (int rr = 0; rr < 4; ++rr) {
        int m = t0 * 128 + wrow * WM + a * 16 + q * 4 + rr;
        Z[((size_t)r * M_ROWS + m) * COUTP + o] = (__bf16)acc[a][b][rr];
      }
    }
  }
}

// ---------------------------------------------------------------------------
// FIR GEMM, BK=64, K=448: Y(112 x 64-slice) = Afir(112x448) @ Z(448xN).
// B transposed in LDS (k-pair packed b32, [n][35-dword stride]).
// Double-buffered (2x23296B), counted-wait pipeline (R13). K-loop fully
// unrolled; MFMAs guarded by constexpr FIRNEED band table (53/98 issued,
// guards constant-fold). Staging untouched (load-skip measured -5us, R14/15).
// STATS: fused BN sum/sumsq atomics.  SOFTMAX (L3): in-LDS softmax + t-sum.
// ---------------------------------------------------------------------------
template <int COUTP, bool STATS, bool SOFTMAX>
__global__ __launch_bounds__(256, 2)
void fir_gemm64(const __bf16* __restrict__ Af, const __bf16* __restrict__ Z,
                __bf16* __restrict__ Yout, float* __restrict__ stats,
                float* __restrict__ outp, int N) {
  __shared__ __align__(16) unsigned char smem[46592];  // 2 x (14336 + 8960)

  const int tid = threadIdx.x;
  const int w = tid >> 6, lane = tid & 63;
  const int q = lane >> 4, ln = lane & 15;
  const int srow8 = lane >> 3, s8 = lane & 7;
  const int kp = tid >> 3;    // 0..31
  const int noct = tid & 7;   // 0..7
  const int nb = blockIdx.x * 64;

  v4f acc[7];
#pragma unroll
  for (int a = 0; a < 7; ++a) acc[a] = v4f{0.f, 0.f, 0.f, 0.f};

  uint4 r0, r1;  // B-regs for the tile about to be written to LDS

  // buffer b: sA = smem + b*23296 (14336 B), sBu = smem + b*23296 + 14336
#define SA_BUF(b) ((__bf16*)(smem + (b) * 23296))
#define SB_BUF(b) ((uint32*)(smem + (b) * 23296 + 14336))

  // ---- prologue: issue tile 0 ----
  {
    __bf16* sA = SA_BUF(0);
    for (int j = w; j < 14; j += 4) {
      int m = j * 8 + srow8;
      int g = s8 ^ (m & 7);
      gl_lds16(Af + (size_t)m * K_FIR + 0 + g * 8, &sA[j * 512]);
    }
    const __bf16* zp = Z + (size_t)(0 + kp * 2) * N + nb + noct * 8;
    r0 = *(const uint4*)zp;
    r1 = *(const uint4*)(zp + N);
  }

#pragma unroll
  for (int i = 0; i < 7; ++i) {
    const int cb = i & 1;
    // wait: tile i's A-DMA + B-regs (issued one compute-phase ago)
    asm volatile("s_waitcnt vmcnt(0)" ::: "memory");
    // write B(i) -> LDS (transposed, k-pair packed)
    {
      uint32* sBu = SB_BUF(cb);
      const ushort_t* p0 = (const ushort_t*)&r0;
      const ushort_t* p1 = (const ushort_t*)&r1;
#pragma unroll
      for (int j = 0; j < 8; ++j) {
        uint32 val = (uint32)p0[j] | ((uint32)p1[j] << 16);
        sBu[(noct * 8 + j) * 35 + kp] = val;
      }
    }
    // issue tile i+1 (in flight across compute(i))
    if (i < 6) {
      int kc = (i + 1) * 64;
      __bf16* sA = SA_BUF(cb ^ 1);
      for (int j = w; j < 14; j += 4) {
        int m = j * 8 + srow8;
        int g = s8 ^ (m & 7);
        gl_lds16(Af + (size_t)m * K_FIR + kc + g * 8, &sA[j * 512]);
      }
      const __bf16* zp = Z + (size_t)(kc + kp * 2) * N + nb + noct * 8;
      r0 = *(const uint4*)zp;
      r1 = *(const uint4*)(zp + N);
    }
    asm volatile("s_waitcnt lgkmcnt(0)" ::: "memory");  // our ds_writes done
    __builtin_amdgcn_s_barrier();                       // raw: no vmcnt drain

    {
      __bf16* sA = SA_BUF(cb);
      uint32* sBu = SB_BUF(cb);
#pragma unroll
      for (int s = 0; s < 2; ++s) {
        v8bf af[7];
#pragma unroll
        for (int a = 0; a < 7; ++a) {
          if (FIRNEED.v[2 * i + s][a]) {
            int m = a * 16 + ln;
            af[a] = *(const v8bf*)&sA[m * 64 + ((((s << 2) | q) ^ (m & 7)) * 8)];
          }
        }
        int base = (w * 16 + ln) * 35 + s * 16 + q * 4;
        uint32 tmp[4] = {sBu[base], sBu[base + 1], sBu[base + 2], sBu[base + 3]};
        v8bf bfr = *(const v8bf*)tmp;
#pragma unroll
        for (int a = 0; a < 7; ++a) {
          if (FIRNEED.v[2 * i + s][a])
            acc[a] = __builtin_amdgcn_mfma_f32_16x16x32_bf16(af[a], bfr, acc[a], 0, 0, 0);
        }
      }
    }
    __builtin_amdgcn_s_barrier();  // all waves done reading before buf reuse
  }

  int ng = nb + w * 16 + ln;
  if (!SOFTMAX) {
    float s = 0.f, ss = 0.f;
#pragma unroll
    for (int a = 0; a < 7; ++a) {
#pragma unroll
      for (int rr = 0; rr < 4; ++rr) {
        int t = a * 16 + q * 4 + rr;
        float v = acc[a][rr];
        if (t < 100) {
          Yout[(size_t)t * N + ng] = (__bf16)v;
          s += v; ss += v * v;
        }
      }
    }
    if (STATS) {
      s += __shfl_xor(s, 16); ss += __shfl_xor(ss, 16);
      s += __shfl_xor(s, 32); ss += __shfl_xor(ss, 32);
      if (q == 0) {
        int o = ng & (COUTP - 1);
        atomicAdd(&stats[o], s);
        atomicAdd(&stats[COUTP + o], ss);
      }
    }
  } else {
    // L3: this block holds all t and all o for 2 batch entries.
    float* smx = (float*)smem;               // [100][65] = 26000 B (reuses bufs)
    float* lacc = (float*)(smem + 26000);    // 40 floats
    int col = w * 16 + ln;
#pragma unroll
    for (int a = 0; a < 7; ++a) {
#pragma unroll
      for (int rr = 0; rr < 4; ++rr) {
        int t = a * 16 + q * 4 + rr;
        if (t < 100) smx[t * 65 + col] = acc[a][rr];
      }
    }
    if (tid < 64) lacc[tid & 63] = 0.f;
    __syncthreads();
    if (tid < 200) {
      int bl = tid / 100, t = tid - bl * 100;
      const float* rr = &smx[t * 65 + bl * 32];
      float v[20], m = -1e30f;
#pragma unroll
      for (int o = 0; o < 20; ++o) { v[o] = rr[o]; m = fmaxf(m, v[o]); }
      float sum = 0.f;
#pragma unroll
      for (int o = 0; o < 20; ++o) { v[o] = expf(v[o] - m); sum += v[o]; }
      float inv = 1.f / sum;
#pragma unroll
      for (int o = 0; o < 20; ++o) atomicAdd(&lacc[bl * 20 + o], v[o] * inv);
    }
    __syncthreads();
    if (tid < 40) {
      int bl = tid / 20, o = tid - bl * 20;
      int b = (nb >> 5) + bl;
      outp[b * 20 + o] = lacc[bl * 20 + o];
    }
  }
#undef SA_BUF
#undef SB_BUF
}

// normalize + relu, bf16x8 vectorized, in-place on Y
__global__ __launch_bounds__(256)
void bn_apply_relu8(__bf16* __restrict__ h, const float* __restrict__ stats,
                    const float* __restrict__ gamma, const float* __restrict__ beta) {
  int idx = blockIdx.x * 256 + threadIdx.x;
  int co = (idx & 31) * 8;
  size_t row = (size_t)(idx >> 5);
  __bf16* p = h + row * 256 + co;
  uint4 raw = *(const uint4*)p;
  const ushort_t* pr = (const ushort_t*)&raw;
  uint4 outv;
  ushort_t* po = (ushort_t*)&outv;
#pragma unroll
  for (int j = 0; j < 8; ++j) {
    int c = co + j;
    float mean = stats[c] * (1.f / 12800.f);
    float var = stats[256 + c] * (1.f / 12800.f) - mean * mean;
    float inv = rsqrtf(var + 1e-5f) * gamma[c];
    uint32 u = (uint32)pr[j] << 16;
    float xv; __builtin_memcpy(&xv, &u, 4);
    float v = (xv - mean) * inv + beta[c];
    v = fmaxf(v, 0.f);
    __bf16 bv = (__bf16)v;
    po[j] = *(const ushort_t*)&bv;
  }
  *(uint4*)p = outv;
}

// ---------------------------------------------------------------------------

extern "C" void kernel_launch(void* const* d_in, const int* in_sizes, int n_in,
                              void* d_out, int out_size, void* d_ws, size_t ws_size,
                              hipStream_t stream) {
  const float* x  = (const float*)d_in[0];
  const float* W1 = (const float*)d_in[1];
  const float* P1 = (const float*)d_in[2];
  const float* W2 = (const float*)d_in[3];
  const float* P2 = (const float*)d_in[4];
  const float* W3 = (const float*)d_in[5];
  const float* P3 = (const float*)d_in[6];
  const float* g1 = (const float*)d_in[7];
  const float* b1 = (const float*)d_in[8];
  const float* g2 = (const float*)d_in[9];
  const float* b2 = (const float*)d_in[10];
  float* out = (float*)d_out;

  constexpr size_t XB_B  = (size_t)M_ROWS * 704 * 2;        // 18,022,400
  constexpr size_t Z_B   = (size_t)K_FIR * 32768 * 2;       // 29,360,128
  constexpr size_t Y12_B = (size_t)M_ROWS * 256 * 2;        //  6,553,600
  constexpr size_t W1_B  = (size_t)R_RANK * 256 * 704 * 2;  //  1,441,792
  constexpr size_t W2_B  = (size_t)R_RANK * 256 * 256 * 2;  //    524,288
  constexpr size_t W3_B  = (size_t)R_RANK * 32 * 256 * 2;   //     65,536
  constexpr size_t AF_B  = (size_t)112 * K_FIR * 2;         //    100,352
  constexpr size_t ST_B  = 4096;
  constexpr size_t TOTAL = XB_B + Z_B + Y12_B + W1_B + W2_B + W3_B + AF_B + ST_B;
  if (ws_size < TOTAL) return;

  char* ws = (char*)d_ws;
  size_t off = 0;
  __bf16* Xb   = (__bf16*)(ws + off); off += XB_B;
  __bf16* Zb   = (__bf16*)(ws + off); off += Z_B;
  __bf16* Yb   = (__bf16*)(ws + off); off += Y12_B;   // Y1 then Y2 (in-place BN)
  __bf16* Wr1  = (__bf16*)(ws + off); off += W1_B;
  __bf16* Wr2  = (__bf16*)(ws + off); off += W2_B;
  __bf16* Wr3  = (__bf16*)(ws + off); off += W3_B;
  __bf16* Afir = (__bf16*)(ws + off); off += AF_B;
  float*  stats1 = (float*)(ws + off);
  float*  stats2 = stats1 + 512;

  // fused setup: 256+256+32+196+2200+1 blocks
  setup_all<<<dim3(2941), 256, 0, stream>>>(x, W1, P1, W2, P2, W3, P3,
                                            Xb, Wr1, Wr2, Wr3, Afir, stats1);

  // layer 1: GEMM (12800 x 1024 x 704), BLK_N=256 -> FIR (+stats) -> BN in-place
  gemm_rk64<704, 256, 2, 2, 8><<<dim3(100, 4), 256, 0, stream>>>(Xb, Wr1, Zb);
  fir_gemm64<256, true, false><<<dim3(512), 256, 0, stream>>>(
      Afir, Zb, Yb, stats1, nullptr, 32768);
  bn_apply_relu8<<<dim3(1600), 256, 0, stream>>>(Yb, stats1, g1, b1);

  // layer 2: GEMM (12800 x 1024 x 256), BLK_N=256
  gemm_rk64<256, 256, 2, 2, 8><<<dim3(100, 4), 256, 0, stream>>>(Yb, Wr2, Zb);
  fir_gemm64<256, true, false><<<dim3(512), 256, 0, stream>>>(
      Afir, Zb, Yb, stats2, nullptr, 32768);
  bn_apply_relu8<<<dim3(1600), 256, 0, stream>>>(Yb, stats2, g2, b2);

  // layer 3: GEMM (12800 x 128 x 256), then FIR + fused softmax/time-sum
  gemm_rk64<256, 64, 2, 2, 5><<<dim3(100, 2), 256, 0, stream>>>(Yb, Wr3, Zb);
  fir_gemm64<32, false, true><<<dim3(64), 256, 0, stream>>>(
      Afir, Zb, nullptr, nullptr, out, 4096);
}